// Round 4
// baseline (151.899 us; speedup 1.0000x reference)
//
#include <hip/hip_runtime.h>

#define Bz 4
#define Tz 4096
#define Ez 1024
#define Hz 16
#define Sz 64
#define Dz 64
#define MTz (Bz*Tz)   // 16384

using f32x4  = __attribute__((ext_vector_type(4))) float;
using short8 = __attribute__((ext_vector_type(8))) short;

__device__ __forceinline__ unsigned f2bf(float f){
  unsigned u = __builtin_bit_cast(unsigned, f);
  u = u + 0x7FFFu + ((u >> 16) & 1u);
  return (u >> 16);
}

#define GLL16(gp, lp) __builtin_amdgcn_global_load_lds( \
    (const __attribute__((address_space(1))) unsigned int*)(gp), \
    (__attribute__((address_space(3))) unsigned int*)(lp), 16, 0, 0)

// ---------------- P0: Mh[h]=C_w[h]@sm[h], a_state, bias_f  (16 blocks) ---------------
__global__ __launch_bounds__(256) void p0_pre(const float* __restrict__ state,
                                              const float* __restrict__ A_w,
                                              const float* __restrict__ A_b,
                                              const float* __restrict__ C_w,
                                              const float* __restrict__ C_b,
                                              const float* __restrict__ sm,
                                              float* __restrict__ a_state,
                                              float* __restrict__ Mh,
                                              float* __restrict__ bias_f){
  __shared__ float asl[4][64];
  const int h = blockIdx.x, tid = threadIdx.x;
  { // a_state[h][b][s]
    const int b = tid >> 6, s = tid & 63;
    const float* aw = A_w + (size_t)(h*64 + s)*64;
    const float* st = state + (size_t)(h*4 + b)*64;
    float a0=A_b[h*64+s], a1=0.f, a2=0.f, a3=0.f;
    #pragma unroll 4
    for (int j = 0; j < 64; j += 4){
      a0 += aw[j]*st[j]; a1 += aw[j+1]*st[j+1];
      a2 += aw[j+2]*st[j+2]; a3 += aw[j+3]*st[j+3];
    }
    float v = (a0+a1)+(a2+a3);
    a_state[(h*4 + b)*64 + s] = v;
    asl[b][s] = v;
  }
  // Mh[h][d][dp] = sum_s C_w[h][d][s]*sm[h][s][dp]
  #pragma unroll
  for (int q = 0; q < 4; ++q){
    const int d = q*16 + (tid >> 4), dp0 = (tid & 15)*4;
    const float* cw  = C_w + (size_t)(h*64 + d)*64;
    const float* smh = sm + (size_t)h*4096 + dp0;
    float ax=0.f, ay=0.f, az=0.f, aw=0.f;
    #pragma unroll 8
    for (int s = 0; s < 64; ++s){
      float c = cw[s];
      float4 m4 = *(const float4*)&smh[s*64];
      ax += c*m4.x; ay += c*m4.y; az += c*m4.z; aw += c*m4.w;
    }
    *(float4*)&Mh[(size_t)h*4096 + d*64 + dp0] = make_float4(ax,ay,az,aw);
  }
  __syncthreads();
  { // bias_f[b][h*64+d] = C_b + C_w[h][d]·asl[b]
    const int b = tid >> 6, d = tid & 63;
    const float* cw = C_w + (size_t)(h*64 + d)*64;
    float a0=C_b[h*64+d], a1=0.f, a2=0.f, a3=0.f;
    #pragma unroll 4
    for (int s = 0; s < 64; s += 4){
      a0 += cw[s]*asl[b][s]; a1 += cw[s+1]*asl[b][s+1];
      a2 += cw[s+2]*asl[b][s+2]; a3 += cw[s+3]*asl[b][s+3];
    }
    bias_f[b*1024 + h*64 + d] = (a0+a1)+(a2+a3);
  }
}

// ---------------- P1: Wb (blocks 0..63, 16 e-rows each) ; constb (64..79) ------------
__global__ __launch_bounds__(256) void p1_pre(const float* __restrict__ Wo,
                                              const float* __restrict__ Mh,
                                              const float* __restrict__ bias_f,
                                              const float* __restrict__ bo,
                                              unsigned short* __restrict__ Wb,
                                              float* __restrict__ constb){
  const int blk = blockIdx.x, tid = threadIdx.x;
  if (blk < 64){
    const int e = blk*16 + (tid >> 4), dp0 = (tid & 15)*4;
    #pragma unroll 4
    for (int h = 0; h < 16; ++h){
      const float* wo = Wo + (size_t)e*1024 + h*64;
      const float* mh = Mh + (size_t)h*4096 + dp0;
      float ax=0.f, ay=0.f, az=0.f, aw=0.f;
      #pragma unroll 4
      for (int d4 = 0; d4 < 16; ++d4){
        float4 w4 = *(const float4*)&wo[d4*4];
        float4 m0 = *(const float4*)&mh[(d4*4+0)*64];
        float4 m1 = *(const float4*)&mh[(d4*4+1)*64];
        float4 m2 = *(const float4*)&mh[(d4*4+2)*64];
        float4 m3 = *(const float4*)&mh[(d4*4+3)*64];
        ax += w4.x*m0.x + w4.y*m1.x + w4.z*m2.x + w4.w*m3.x;
        ay += w4.x*m0.y + w4.y*m1.y + w4.z*m2.y + w4.w*m3.y;
        az += w4.x*m0.z + w4.y*m1.z + w4.z*m2.z + w4.w*m3.z;
        aw += w4.x*m0.w + w4.y*m1.w + w4.z*m2.w + w4.w*m3.w;
      }
      uint2 pk = make_uint2(f2bf(ax) | (f2bf(ay)<<16), f2bf(az) | (f2bf(aw)<<16));
      *(uint2*)&Wb[(size_t)e*1024 + h*64 + dp0] = pk;
    }
  } else {
    int idx = (blk - 64)*256 + tid;
    int b = idx >> 10, e = idx & 1023;
    const float4* wo = (const float4*)(Wo + (size_t)e*1024);
    const float4* bf = (const float4*)(bias_f + (size_t)b*1024);
    float ax=0.f, ay=0.f, az=0.f, aw=0.f;
    for (int f4 = 0; f4 < 256; ++f4){
      float4 w = wo[f4], v = bf[f4];
      ax += w.x*v.x; ay += w.y*v.y; az += w.z*v.z; aw += w.w*v.w;
    }
    constb[b*1024 + e] = bo[e] + ((ax+ay)+(az+aw));
  }
}

// ---------------- K4: new_state (MFMA) + emit xb2 (fragment layout) ------------------
// grid: b(4) x h(16) x tb(32) = 2048 blocks, 256 thr, tile 128(t) x 64(s)
// xb2 layout: elem (r,k) -> [((r>>4)*32 + (k>>5))*512 + (r&15)*32 + ((k>>3)&3)*8 + (k&7)]
__global__ __launch_bounds__(256) void k4_ns(const float* __restrict__ x,
                                             const float* __restrict__ sm,
                                             const float* __restrict__ a_state,
                                             unsigned short* __restrict__ xb2,
                                             float* __restrict__ out2){
  __shared__ alignas(16) unsigned short Xs[128*72];
  __shared__ alignas(16) unsigned short Ss[64*72];
  const int lin = blockIdx.x;
  const int tb = lin & 31, h = (lin >> 5) & 15, b = lin >> 9;
  const int tid = threadIdx.x;
  const int lane = tid & 63, w = tid >> 6;
  const int l15 = lane & 15, l4 = lane >> 4;

  { // stage sm[h] (f32) -> Ss bf16 (row stride 72), 4 chunks of float4 per thread
    const float* src = sm + (size_t)h*4096;
    #pragma unroll
    for (int cc = 0; cc < 4; ++cc){
      int c = cc*256 + tid;                // 1024 chunks of 4 floats
      int s = c >> 4, c4 = c & 15;
      float4 v = *(const float4*)&src[s*64 + c4*4];
      uint2 pk = make_uint2(f2bf(v.x) | (f2bf(v.y)<<16), f2bf(v.z) | (f2bf(v.w)<<16));
      *(uint2*)&Ss[s*72 + c4*4] = pk;
    }
  }
  { // stage x slice -> Xs bf16 (stride 72) and xb2 global (fragment layout)
    const int row0 = b*Tz + tb*128;
    #pragma unroll
    for (int it = 0; it < 4; ++it){
      int id = it*256 + tid;               // 1024 chunks of 8 floats
      int r = id >> 3, c8 = id & 7;
      const float* px = x + (size_t)(row0 + r)*1024 + h*64 + c8*8;
      float4 v0 = *(const float4*)px, v1 = *(const float4*)(px + 4);
      uint4 pk;
      pk.x = f2bf(v0.x) | (f2bf(v0.y)<<16);
      pk.y = f2bf(v0.z) | (f2bf(v0.w)<<16);
      pk.z = f2bf(v1.x) | (f2bf(v1.y)<<16);
      pk.w = f2bf(v1.z) | (f2bf(v1.w)<<16);
      *(uint4*)&Xs[r*72 + c8*8] = pk;
      int rg = row0 + r;
      int kt = 2*h + (c8 >> 2), l4c = c8 & 3;
      size_t dst = ((size_t)((rg >> 4)*32 + kt)*16 + (rg & 15))*32 + l4c*8;
      *(uint4*)(xb2 + dst) = pk;
    }
  }
  __syncthreads();

  // acc[i][j]: swapped layout -> D regs = s, D cols(l15) = t
  f32x4 acc[2][4];
  #pragma unroll
  for (int j = 0; j < 4; ++j){
    float4 as4 = *(const float4*)&a_state[(h*4 + b)*64 + j*16 + l4*4];
    f32x4 a0; a0[0]=as4.x; a0[1]=as4.y; a0[2]=as4.z; a0[3]=as4.w;
    acc[0][j] = a0; acc[1][j] = a0;
  }
  #pragma unroll
  for (int kk = 0; kk < 2; ++kk){
    short8 a[2], bb[4];
    #pragma unroll
    for (int i = 0; i < 2; ++i)
      a[i] = *(const short8*)(&Xs[(w*32 + i*16 + l15)*72 + kk*32 + l4*8]);
    #pragma unroll
    for (int j = 0; j < 4; ++j)
      bb[j] = *(const short8*)(&Ss[(j*16 + l15)*72 + kk*32 + l4*8]);
    #pragma unroll
    for (int i = 0; i < 2; ++i)
      #pragma unroll
      for (int j = 0; j < 4; ++j)
        acc[i][j] = __builtin_amdgcn_mfma_f32_16x16x32_bf16(bb[j], a[i], acc[i][j], 0, 0, 0);
  }
  const size_t base = (size_t)h*1048576 + ((size_t)b*4096 + tb*128)*64;
  #pragma unroll
  for (int i = 0; i < 2; ++i)
    #pragma unroll
    for (int j = 0; j < 4; ++j){
      float4 o = make_float4(acc[i][j][0], acc[i][j][1], acc[i][j][2], acc[i][j][3]);
      *(float4*)(out2 + base + (size_t)(w*32 + i*16 + l15)*64 + j*16 + l4*4) = o;
    }
}

// ---------------- K5: out = xb2 @ Wb^T + const ---------------------------------------
// 256x256, BK=32, 512 thr (8 waves 2Mx4N). A: direct global frag loads (reg dbuf).
// B: 4-deep LDS via GLL, XOR-swizzled reads. vmcnt(2) boundary + barrier per tile.
__global__ __launch_bounds__(512, 2) void k5_gemm(const unsigned short* __restrict__ xb2,
                                                  const unsigned short* __restrict__ Wb,
                                                  const float* __restrict__ constb,
                                                  float* __restrict__ out){
  __shared__ alignas(16) unsigned short ldsB[4][8192];   // [buf][256 rows x 32 bf16]
  const int blk = blockIdx.x;
  const int swz = (blk & 7)*32 + (blk >> 3);     // 256 blocks, XCD-contiguous
  const int bm = (swz >> 2)*256, bn = (swz & 3)*256;
  const int tid = threadIdx.x;
  const int lane = tid & 63, w = tid >> 6;       // 8 waves
  const int l15 = lane & 15, l4 = lane >> 4;
  const int wr = w >> 2, wc = w & 3;             // 2 (M) x 4 (N)

  // B staging source (inverse-swizzled), LDS dest linear
  const unsigned short* srcB[2];
  #pragma unroll
  for (int q = 0; q < 2; ++q){
    int L = q*512 + w*64 + lane;
    int bbt = ((L>>2)&1) ^ ((L>>4)&1);
    int r = (L>>3)*2 + bbt;
    int g = (L&3) ^ ((((L>>3)&1)<<1) | bbt);
    srcB[q] = Wb + (size_t)(bn + r)*1024 + g*8;
  }
  const int dstoff = w*64*8;
  const int lane_off = ((l15*4 + l4) ^ (l15 & 7))*8;

  // A fragment base: lane (l15,l4) reads rows (..+l15), k-chunk l4*8
  const unsigned short* aP = xb2 + ((size_t)((bm >> 4) + wr*8)*32)*512 + l15*32 + l4*8;
  // afr[i] for tile t: aP + i*16384 + t*512

  f32x4 acc[8][4] = {};
  short8 Aa[8], Ab[8];

  // prologue: B tiles 0..2 via GLL, A tile 0 into Aa; conservative drain
  #pragma unroll
  for (int t = 0; t < 3; ++t){
    #pragma unroll
    for (int q = 0; q < 2; ++q) GLL16(srcB[q] + t*32, &ldsB[t][q*4096 + dstoff]);
  }
  #pragma unroll
  for (int i = 0; i < 8; ++i) Aa[i] = *(const short8*)(aP + i*16384);
  asm volatile("s_waitcnt vmcnt(0)" ::: "memory");
  __builtin_amdgcn_s_barrier();
  asm volatile("" ::: "memory");

#define K5_TILE(T, CUR, NXT)                                                        \
  {                                                                                 \
    const int t_ = (T);                                                             \
    const unsigned short* Bt = &ldsB[t_ & 3][0];                                    \
    short8 bfr0 = *(const short8*)(Bt + (wc*64 +  0)*32 + lane_off);                \
    short8 bfr1 = *(const short8*)(Bt + (wc*64 + 16)*32 + lane_off);                \
    short8 bfr2 = *(const short8*)(Bt + (wc*64 + 32)*32 + lane_off);                \
    short8 bfr3 = *(const short8*)(Bt + (wc*64 + 48)*32 + lane_off);                \
    if (t_ < 31){                                                                   \
      NXT[0] = *(const short8*)(aP + 0*16384 + (t_+1)*512);                         \
      NXT[1] = *(const short8*)(aP + 1*16384 + (t_+1)*512);                         \
      NXT[2] = *(const short8*)(aP + 2*16384 + (t_+1)*512);                         \
      NXT[3] = *(const short8*)(aP + 3*16384 + (t_+1)*512);                         \
    }                                                                               \
    __builtin_amdgcn_s_setprio(1);                                                  \
    acc[0][0]=__builtin_amdgcn_mfma_f32_16x16x32_bf16(bfr0,CUR[0],acc[0][0],0,0,0); \
    acc[0][1]=__builtin_amdgcn_mfma_f32_16x16x32_bf16(bfr1,CUR[0],acc[0][1],0,0,0); \
    acc[0][2]=__builtin_amdgcn_mfma_f32_16x16x32_bf16(bfr2,CUR[0],acc[0][2],0,0,0); \
    acc[0][3]=__builtin_amdgcn_mfma_f32_16x16x32_bf16(bfr3,CUR[0],acc[0][3],0,0,0); \
    acc[1][0]=__builtin_amdgcn_mfma_f32_16x16x32_bf16(bfr0,CUR[1],acc[1][0],0,0,0); \
    acc[1][1]=__builtin_amdgcn_mfma_f32_16x16x32_bf16(bfr1,CUR[1],acc[1][1],0,0,0); \
    acc[1][2]=__builtin_amdgcn_mfma_f32_16x16x32_bf16(bfr2,CUR[1],acc[1][2],0,0,0); \
    acc[1][3]=__builtin_amdgcn_mfma_f32_16x16x32_bf16(bfr3,CUR[1],acc[1][3],0,0,0); \
    __builtin_amdgcn_s_setprio(0);                                                  \
    if (t_ < 31){                                                                   \
      NXT[4] = *(const short8*)(aP + 4*16384 + (t_+1)*512);                         \
      NXT[5] = *(const short8*)(aP + 5*16384 + (t_+1)*512);                         \
      NXT[6] = *(const short8*)(aP + 6*16384 + (t_+1)*512);                         \
      NXT[7] = *(const short8*)(aP + 7*16384 + (t_+1)*512);                         \
    }                                                                               \
    __builtin_amdgcn_s_setprio(1);                                                  \
    acc[2][0]=__builtin_amdgcn_mfma_f32_16x16x32_bf16(bfr0,CUR[2],acc[2][0],0,0,0); \
    acc[2][1]=__builtin_amdgcn_mfma_f32_16x16x32_bf16(bfr1,CUR[2],acc[2][1],0,0,0); \
    acc[2][2]=__builtin_amdgcn_mfma_f32_16x16x32_bf16(bfr2,CUR[2],acc[2][2],0,0,0); \
    acc[2][3]=__builtin_amdgcn_mfma_f32_16x16x32_bf16(bfr3,CUR[2],acc[2][3],0,0,0); \
    acc[3][0]=__builtin_amdgcn_mfma_f32_16x16x32_bf16(bfr0,CUR[3],acc[3][0],0,0,0); \
    acc[3][1]=__builtin_amdgcn_mfma_f32_16x16x32_bf16(bfr1,CUR[3],acc[3][1],0,0,0); \
    acc[3][2]=__builtin_amdgcn_mfma_f32_16x16x32_bf16(bfr2,CUR[3],acc[3][2],0,0,0); \
    acc[3][3]=__builtin_amdgcn_mfma_f32_16x16x32_bf16(bfr3,CUR[3],acc[3][3],0,0,0); \
    __builtin_amdgcn_s_setprio(0);                                                  \
    if (t_ <= 28){                                                                  \
      GLL16(srcB[0] + (t_+3)*32, &ldsB[(t_+3) & 3][0*4096 + dstoff]);               \
    }                                                                               \
    __builtin_amdgcn_s_setprio(1);                                                  \
    acc[4][0]=__builtin_amdgcn_mfma_f32_16x16x32_bf16(bfr0,CUR[4],acc[4][0],0,0,0); \
    acc[4][1]=__builtin_amdgcn_mfma_f32_16x16x32_bf16(bfr1,CUR[4],acc[4][1],0,0,0); \
    acc[4][2]=__builtin_amdgcn_mfma_f32_16x16x32_bf16(bfr2,CUR[4],acc[4][2],0,0,0); \
    acc[4][3]=__builtin_amdgcn_mfma_f32_16x16x32_bf16(bfr3,CUR[4],acc[4][3],0,0,0); \
    acc[5][0]=__builtin_amdgcn_mfma_f32_16x16x32_bf16(bfr0,CUR[5],acc[5][0],0,0,0); \
    acc[5][1]=__builtin_amdgcn_mfma_f32_16x16x32_bf16(bfr1,CUR[5],acc[5][1],0,0,0); \
    acc[5][2]=__builtin_amdgcn_mfma_f32_16x16x32_bf16(bfr2,CUR[5],acc[5][2],0,0,0); \
    acc[5][3]=__builtin_amdgcn_mfma_f32_16x16x32_bf16(bfr3,CUR[5],acc[5][3],0,0,0); \
    __builtin_amdgcn_s_setprio(0);                                                  \
    if (t_ <= 28){                                                                  \
      GLL16(srcB[1] + (t_+3)*32, &ldsB[(t_+3) & 3][1*4096 + dstoff]);               \
    }                                                                               \
    __builtin_amdgcn_s_setprio(1);                                                  \
    acc[6][0]=__builtin_amdgcn_mfma_f32_16x16x32_bf16(bfr0,CUR[6],acc[6][0],0,0,0); \
    acc[6][1]=__builtin_amdgcn_mfma_f32_16x16x32_bf16(bfr1,CUR[6],acc[6][1],0,0,0); \
    acc[6][2]=__builtin_amdgcn_mfma_f32_16x16x32_bf16(bfr2,CUR[6],acc[6][2],0,0,0); \
    acc[6][3]=__builtin_amdgcn_mfma_f32_16x16x32_bf16(bfr3,CUR[6],acc[6][3],0,0,0); \
    acc[7][0]=__builtin_amdgcn_mfma_f32_16x16x32_bf16(bfr0,CUR[7],acc[7][0],0,0,0); \
    acc[7][1]=__builtin_amdgcn_mfma_f32_16x16x32_bf16(bfr1,CUR[7],acc[7][1],0,0,0); \
    acc[7][2]=__builtin_amdgcn_mfma_f32_16x16x32_bf16(bfr2,CUR[7],acc[7][2],0,0,0); \
    acc[7][3]=__builtin_amdgcn_mfma_f32_16x16x32_bf16(bfr3,CUR[7],acc[7][3],0,0,0); \
    __builtin_amdgcn_s_setprio(0);                                                  \
    if (t_ <= 28)      { asm volatile("s_waitcnt vmcnt(2)" ::: "memory"); }         \
    else if (t_ < 31)  { asm volatile("s_waitcnt vmcnt(0)" ::: "memory"); }         \
    if (t_ < 31){                                                                   \
      __builtin_amdgcn_s_barrier();                                                 \
      asm volatile("" ::: "memory");                                                \
    }                                                                               \
  }

  for (int tt = 0; tt < 16; ++tt){
    K5_TILE(2*tt,     Aa, Ab);
    K5_TILE(2*tt + 1, Ab, Aa);
  }
#undef K5_TILE

  // epilogue: D cols(l15)=t-row, regs(l4*4+q)=e-col
  const int bb = bm >> 12;
  #pragma unroll
  for (int j = 0; j < 4; ++j){
    int n0 = bn + wc*64 + j*16 + l4*4;
    float4 cv = *(const float4*)&constb[bb*1024 + n0];
    #pragma unroll
    for (int i = 0; i < 8; ++i){
      int trow = bm + wr*128 + i*16 + l15;
      float4 o = make_float4(acc[i][j][0] + cv.x, acc[i][j][1] + cv.y,
                             acc[i][j][2] + cv.z, acc[i][j][3] + cv.w);
      *(float4*)(out + (size_t)trow*1024 + n0) = o;
    }
  }
}

extern "C" void kernel_launch(void* const* d_in, const int* in_sizes, int n_in,
                              void* d_out, int out_size, void* d_ws, size_t ws_size,
                              hipStream_t stream){
  const float* x     = (const float*)d_in[0];
  const float* state = (const float*)d_in[1];
  const float* A_w   = (const float*)d_in[2];
  const float* A_b   = (const float*)d_in[3];
  const float* C_w   = (const float*)d_in[4];
  const float* C_b   = (const float*)d_in[5];
  const float* sm    = (const float*)d_in[6];
  const float* Wo    = (const float*)d_in[7];
  const float* bo    = (const float*)d_in[8];
  float* out  = (float*)d_out;
  float* out2 = out + (size_t)MTz*Ez;

  char* ws = (char*)d_ws;
  float* a_state          = (float*)(ws + 0);                 //  16 KiB
  float* Mh               = (float*)(ws + 16384);             // 256 KiB
  float* bias_f           = (float*)(ws + 278528);            //  16 KiB
  float* constb           = (float*)(ws + 294912);            //  16 KiB
  unsigned short* Wb      = (unsigned short*)(ws + 311296);   //   2 MiB
  unsigned short* xb2     = (unsigned short*)(ws + 2408448);  //  32 MiB

  p0_pre<<<16, 256, 0, stream>>>(state, A_w, A_b, C_w, C_b, sm, a_state, Mh, bias_f);
  p1_pre<<<80, 256, 0, stream>>>(Wo, Mh, bias_f, bo, Wb, constb);
  k4_ns<<<2048, 256, 0, stream>>>(x, sm, a_state, xb2, out2);
  k5_gemm<<<256, 512, 0, stream>>>(xb2, Wb, constb, out);
}

// Round 5
// 139.621 us; speedup vs baseline: 1.0879x; 1.0879x over previous
//
#include <hip/hip_runtime.h>

#define Bz 4
#define Tz 4096
#define Ez 1024
#define Hz 16
#define Sz 64
#define Dz 64
#define MTz (Bz*Tz)   // 16384

using f32x4  = __attribute__((ext_vector_type(4))) float;
using short8 = __attribute__((ext_vector_type(8))) short;

__device__ __forceinline__ unsigned f2bf(float f){
  unsigned u = __builtin_bit_cast(unsigned, f);
  u = u + 0x7FFFu + ((u >> 16) & 1u);
  return (u >> 16);
}

#define GLL16(gp, lp) __builtin_amdgcn_global_load_lds( \
    (const __attribute__((address_space(1))) unsigned int*)(gp), \
    (__attribute__((address_space(3))) unsigned int*)(lp), 16, 0, 0)

// ---------------- P0: Mh[h]=C_w[h]@sm[h], a_state, bias_f  (16 blocks) ---------------
__global__ __launch_bounds__(256) void p0_pre(const float* __restrict__ state,
                                              const float* __restrict__ A_w,
                                              const float* __restrict__ A_b,
                                              const float* __restrict__ C_w,
                                              const float* __restrict__ C_b,
                                              const float* __restrict__ sm,
                                              float* __restrict__ a_state,
                                              float* __restrict__ Mh,
                                              float* __restrict__ bias_f){
  __shared__ float asl[4][64];
  const int h = blockIdx.x, tid = threadIdx.x;
  { // a_state[h][b][s]
    const int b = tid >> 6, s = tid & 63;
    const float* aw = A_w + (size_t)(h*64 + s)*64;
    const float* st = state + (size_t)(h*4 + b)*64;
    float a0=A_b[h*64+s], a1=0.f, a2=0.f, a3=0.f;
    #pragma unroll 4
    for (int j = 0; j < 64; j += 4){
      a0 += aw[j]*st[j]; a1 += aw[j+1]*st[j+1];
      a2 += aw[j+2]*st[j+2]; a3 += aw[j+3]*st[j+3];
    }
    float v = (a0+a1)+(a2+a3);
    a_state[(h*4 + b)*64 + s] = v;
    asl[b][s] = v;
  }
  // Mh[h][d][dp] = sum_s C_w[h][d][s]*sm[h][s][dp]
  #pragma unroll
  for (int q = 0; q < 4; ++q){
    const int d = q*16 + (tid >> 4), dp0 = (tid & 15)*4;
    const float* cw  = C_w + (size_t)(h*64 + d)*64;
    const float* smh = sm + (size_t)h*4096 + dp0;
    float ax=0.f, ay=0.f, az=0.f, aw=0.f;
    #pragma unroll 8
    for (int s = 0; s < 64; ++s){
      float c = cw[s];
      float4 m4 = *(const float4*)&smh[s*64];
      ax += c*m4.x; ay += c*m4.y; az += c*m4.z; aw += c*m4.w;
    }
    *(float4*)&Mh[(size_t)h*4096 + d*64 + dp0] = make_float4(ax,ay,az,aw);
  }
  __syncthreads();
  { // bias_f[b][h*64+d] = C_b + C_w[h][d]·asl[b]
    const int b = tid >> 6, d = tid & 63;
    const float* cw = C_w + (size_t)(h*64 + d)*64;
    float a0=C_b[h*64+d], a1=0.f, a2=0.f, a3=0.f;
    #pragma unroll 4
    for (int s = 0; s < 64; s += 4){
      a0 += cw[s]*asl[b][s]; a1 += cw[s+1]*asl[b][s+1];
      a2 += cw[s+2]*asl[b][s+2]; a3 += cw[s+3]*asl[b][s+3];
    }
    bias_f[b*1024 + h*64 + d] = (a0+a1)+(a2+a3);
  }
}

// ---------------- P1: Wb (blocks 0..63, 16 e-rows each) ; constb (64..79) ------------
__global__ __launch_bounds__(256) void p1_pre(const float* __restrict__ Wo,
                                              const float* __restrict__ Mh,
                                              const float* __restrict__ bias_f,
                                              const float* __restrict__ bo,
                                              unsigned short* __restrict__ Wb,
                                              float* __restrict__ constb){
  const int blk = blockIdx.x, tid = threadIdx.x;
  if (blk < 64){
    const int e = blk*16 + (tid >> 4), dp0 = (tid & 15)*4;
    #pragma unroll 4
    for (int h = 0; h < 16; ++h){
      const float* wo = Wo + (size_t)e*1024 + h*64;
      const float* mh = Mh + (size_t)h*4096 + dp0;
      float ax=0.f, ay=0.f, az=0.f, aw=0.f;
      #pragma unroll 4
      for (int d4 = 0; d4 < 16; ++d4){
        float4 w4 = *(const float4*)&wo[d4*4];
        float4 m0 = *(const float4*)&mh[(d4*4+0)*64];
        float4 m1 = *(const float4*)&mh[(d4*4+1)*64];
        float4 m2 = *(const float4*)&mh[(d4*4+2)*64];
        float4 m3 = *(const float4*)&mh[(d4*4+3)*64];
        ax += w4.x*m0.x + w4.y*m1.x + w4.z*m2.x + w4.w*m3.x;
        ay += w4.x*m0.y + w4.y*m1.y + w4.z*m2.y + w4.w*m3.y;
        az += w4.x*m0.z + w4.y*m1.z + w4.z*m2.z + w4.w*m3.z;
        aw += w4.x*m0.w + w4.y*m1.w + w4.z*m2.w + w4.w*m3.w;
      }
      uint2 pk = make_uint2(f2bf(ax) | (f2bf(ay)<<16), f2bf(az) | (f2bf(aw)<<16));
      *(uint2*)&Wb[(size_t)e*1024 + h*64 + dp0] = pk;
    }
  } else {
    int idx = (blk - 64)*256 + tid;
    int b = idx >> 10, e = idx & 1023;
    const float4* wo = (const float4*)(Wo + (size_t)e*1024);
    const float4* bf = (const float4*)(bias_f + (size_t)b*1024);
    float ax=0.f, ay=0.f, az=0.f, aw=0.f;
    for (int f4 = 0; f4 < 256; ++f4){
      float4 w = wo[f4], v = bf[f4];
      ax += w.x*v.x; ay += w.y*v.y; az += w.z*v.z; aw += w.w*v.w;
    }
    constb[b*1024 + e] = bo[e] + ((ax+ay)+(az+aw));
  }
}

// ---------------- K4: new_state (MFMA, swapped operands) + emit xb=bf16(x) -----------
// grid: b(4) x h(16) x tb(32) = 2048 blocks, 256 thr, tile 128(t) x 64(s)
__global__ __launch_bounds__(256) void k4_ns(const float* __restrict__ x,
                                             const float* __restrict__ sm,
                                             const float* __restrict__ a_state,
                                             unsigned short* __restrict__ xb,
                                             float* __restrict__ out2){
  __shared__ alignas(16) unsigned short Xs[128*72];
  __shared__ alignas(16) unsigned short Ss[64*72];
  const int lin = blockIdx.x;
  const int tb = lin & 31, h = (lin >> 5) & 15, b = lin >> 9;
  const int tid = threadIdx.x;
  const int lane = tid & 63, w = tid >> 6;
  const int l15 = lane & 15, l4 = lane >> 4;

  { // stage sm[h] (f32) -> Ss bf16 (row stride 72)
    const float* src = sm + (size_t)h*4096;
    #pragma unroll
    for (int cc = 0; cc < 4; ++cc){
      int c = cc*256 + tid;                // 1024 chunks of 4 floats
      int s = c >> 4, c4 = c & 15;
      float4 v = *(const float4*)&src[s*64 + c4*4];
      uint2 pk = make_uint2(f2bf(v.x) | (f2bf(v.y)<<16), f2bf(v.z) | (f2bf(v.w)<<16));
      *(uint2*)&Ss[s*72 + c4*4] = pk;
    }
  }
  { // stage x slice -> Xs bf16 (stride 72) and xb global (row-major, 16B granules)
    const int row0 = b*Tz + tb*128;
    #pragma unroll
    for (int it = 0; it < 4; ++it){
      int id = it*256 + tid;               // 1024 chunks of 8 floats
      int r = id >> 3, c8 = id & 7;
      const float* px = x + (size_t)(row0 + r)*1024 + h*64 + c8*8;
      float4 v0 = *(const float4*)px, v1 = *(const float4*)(px + 4);
      uint4 pk;
      pk.x = f2bf(v0.x) | (f2bf(v0.y)<<16);
      pk.y = f2bf(v0.z) | (f2bf(v0.w)<<16);
      pk.z = f2bf(v1.x) | (f2bf(v1.y)<<16);
      pk.w = f2bf(v1.z) | (f2bf(v1.w)<<16);
      *(uint4*)&Xs[r*72 + c8*8] = pk;
      *(uint4*)(xb + (size_t)(row0 + r)*1024 + h*64 + c8*8) = pk;
    }
  }
  __syncthreads();

  // acc[i][j]: swapped layout -> D regs = s, D cols(l15) = t
  f32x4 acc[2][4];
  #pragma unroll
  for (int j = 0; j < 4; ++j){
    float4 as4 = *(const float4*)&a_state[(h*4 + b)*64 + j*16 + l4*4];
    f32x4 a0; a0[0]=as4.x; a0[1]=as4.y; a0[2]=as4.z; a0[3]=as4.w;
    acc[0][j] = a0; acc[1][j] = a0;
  }
  #pragma unroll
  for (int kk = 0; kk < 2; ++kk){
    short8 a[2], bb[4];
    #pragma unroll
    for (int i = 0; i < 2; ++i)
      a[i] = *(const short8*)(&Xs[(w*32 + i*16 + l15)*72 + kk*32 + l4*8]);
    #pragma unroll
    for (int j = 0; j < 4; ++j)
      bb[j] = *(const short8*)(&Ss[(j*16 + l15)*72 + kk*32 + l4*8]);
    #pragma unroll
    for (int i = 0; i < 2; ++i)
      #pragma unroll
      for (int j = 0; j < 4; ++j)
        acc[i][j] = __builtin_amdgcn_mfma_f32_16x16x32_bf16(bb[j], a[i], acc[i][j], 0, 0, 0);
  }
  const size_t base = (size_t)h*1048576 + ((size_t)b*4096 + tb*128)*64;
  #pragma unroll
  for (int i = 0; i < 2; ++i)
    #pragma unroll
    for (int j = 0; j < 4; ++j){
      float4 o = make_float4(acc[i][j][0], acc[i][j][1], acc[i][j][2], acc[i][j][3]);
      *(float4*)(out2 + base + (size_t)(w*32 + i*16 + l15)*64 + j*16 + l4*4) = o;
    }
}

// ---------------- K5: out = xb @ Wb^T + const  (R3-proven schedule) -------------------
// 256x256 tile, BK=32, 512 thr (8 waves 2Mx4N), 4 LDS buffers, counted vmcnt(8),
// XOR-swizzled LDS: slot16 = (r*4+g) ^ (r&7)  (inverse applied on global source).
__global__ __launch_bounds__(512, 2) void k5_gemm(const unsigned short* __restrict__ xb,
                                                  const unsigned short* __restrict__ Wb,
                                                  const float* __restrict__ constb,
                                                  float* __restrict__ out){
  __shared__ alignas(16) unsigned short lds[4][2][8192];   // [buf][A/B][256 rows x 32 bf16]
  const int blk = blockIdx.x;
  const int swz = (blk & 7)*32 + (blk >> 3);     // 256 blocks, 8 XCD chunks of 32
  const int bm = (swz >> 2)*256, bn = (swz & 3)*256;
  const int tid = threadIdx.x;
  const int lane = tid & 63, w = tid >> 6;       // 8 waves
  const int l15 = lane & 15, l4 = lane >> 4;
  const int wr = w >> 2, wc = w & 3;             // 2 (M) x 4 (N)

  // staging source mapping: linear slot L -> logical (row r, 16B-seg g)
  const unsigned short* srcA[2];
  const unsigned short* srcB[2];
  #pragma unroll
  for (int q = 0; q < 2; ++q){
    int L = q*512 + w*64 + lane;
    int b = ((L>>2)&1) ^ ((L>>4)&1);
    int r = (L>>3)*2 + b;
    int g = (L&3) ^ ((((L>>3)&1)<<1) | b);
    srcA[q] = xb + (size_t)(bm + r)*1024 + g*8;
    srcB[q] = Wb + (size_t)(bn + r)*1024 + g*8;
  }
  const int dstoff = w*64*8;                      // shorts; + q*4096
  const int lane_off = ((l15*4 + l4) ^ (l15 & 7))*8;  // swizzled frag offset (shorts)

  // prologue: stage tiles 0,1,2 (12 GLL/thread)
  #pragma unroll
  for (int t = 0; t < 3; ++t){
    #pragma unroll
    for (int q = 0; q < 2; ++q) GLL16(srcA[q] + t*32, &lds[t][0][q*4096 + dstoff]);
    #pragma unroll
    for (int q = 0; q < 2; ++q) GLL16(srcB[q] + t*32, &lds[t][1][q*4096 + dstoff]);
  }
  asm volatile("s_waitcnt vmcnt(8)" ::: "memory");
  __builtin_amdgcn_s_barrier();
  asm volatile("" ::: "memory");

  f32x4 acc[8][4] = {};

  for (int t = 0; t < 32; ++t){
    const unsigned short* At = &lds[t & 3][0][0];
    const unsigned short* Bt = &lds[t & 3][1][0];
    const int ts = (t + 3) & 3;
    short8 bfr[4], afr[4];
    // ---- phase A: B-frags + A-frags 0..3, stage A of tile t+3, 16 MFMA
    #pragma unroll
    for (int j = 0; j < 4; ++j)
      bfr[j] = *(const short8*)(Bt + (wc*64 + j*16)*32 + lane_off);
    #pragma unroll
    for (int i = 0; i < 4; ++i)
      afr[i] = *(const short8*)(At + (wr*128 + i*16)*32 + lane_off);
    if (t < 29){
      #pragma unroll
      for (int q = 0; q < 2; ++q) GLL16(srcA[q] + (t+3)*32, &lds[ts][0][q*4096 + dstoff]);
    }
    __builtin_amdgcn_s_setprio(1);
    #pragma unroll
    for (int i = 0; i < 4; ++i)
      #pragma unroll
      for (int j = 0; j < 4; ++j)
        acc[i][j] = __builtin_amdgcn_mfma_f32_16x16x32_bf16(bfr[j], afr[i], acc[i][j], 0, 0, 0);
    __builtin_amdgcn_s_setprio(0);
    // ---- phase B: A-frags 4..7, stage B of tile t+3, 16 MFMA
    #pragma unroll
    for (int i = 0; i < 4; ++i)
      afr[i] = *(const short8*)(At + (wr*128 + (4 + i)*16)*32 + lane_off);
    if (t < 29){
      #pragma unroll
      for (int q = 0; q < 2; ++q) GLL16(srcB[q] + (t+3)*32, &lds[ts][1][q*4096 + dstoff]);
    }
    __builtin_amdgcn_s_setprio(1);
    #pragma unroll
    for (int i = 0; i < 4; ++i)
      #pragma unroll
      for (int j = 0; j < 4; ++j)
        acc[4+i][j] = __builtin_amdgcn_mfma_f32_16x16x32_bf16(bfr[j], afr[i], acc[4+i][j], 0, 0, 0);
    __builtin_amdgcn_s_setprio(0);
    // ---- tile boundary: counted vmcnt (tiles t+2,t+3 stay in flight), barrier
    if (t < 29)       asm volatile("s_waitcnt vmcnt(8)" ::: "memory");
    else if (t == 29) asm volatile("s_waitcnt vmcnt(4)" ::: "memory");
    else if (t == 30) asm volatile("s_waitcnt vmcnt(0)" ::: "memory");
    if (t < 31){
      __builtin_amdgcn_s_barrier();
      asm volatile("" ::: "memory");
    }
  }

  // epilogue: D cols(l15)=t-row, regs(l4*4+q)=e-col
  const int bb = bm >> 12;
  #pragma unroll
  for (int j = 0; j < 4; ++j){
    int n0 = bn + wc*64 + j*16 + l4*4;
    float4 cv = *(const float4*)&constb[bb*1024 + n0];
    #pragma unroll
    for (int i = 0; i < 8; ++i){
      int trow = bm + wr*128 + i*16 + l15;
      float4 o = make_float4(acc[i][j][0] + cv.x, acc[i][j][1] + cv.y,
                             acc[i][j][2] + cv.z, acc[i][j][3] + cv.w);
      *(float4*)(out + (size_t)trow*1024 + n0) = o;
    }
  }
}

extern "C" void kernel_launch(void* const* d_in, const int* in_sizes, int n_in,
                              void* d_out, int out_size, void* d_ws, size_t ws_size,
                              hipStream_t stream){
  const float* x     = (const float*)d_in[0];
  const float* state = (const float*)d_in[1];
  const float* A_w   = (const float*)d_in[2];
  const float* A_b   = (const float*)d_in[3];
  const float* C_w   = (const float*)d_in[4];
  const float* C_b   = (const float*)d_in[5];
  const float* sm    = (const float*)d_in[6];
  const float* Wo    = (const float*)d_in[7];
  const float* bo    = (const float*)d_in[8];
  float* out  = (float*)d_out;
  float* out2 = out + (size_t)MTz*Ez;

  char* ws = (char*)d_ws;
  float* a_state          = (float*)(ws + 0);                 //  16 KiB
  float* Mh               = (float*)(ws + 16384);             // 256 KiB
  float* bias_f           = (float*)(ws + 278528);            //  16 KiB
  float* constb           = (float*)(ws + 294912);            //  16 KiB
  unsigned short* Wb      = (unsigned short*)(ws + 311296);   //   2 MiB
  unsigned short* xb      = (unsigned short*)(ws + 2408448);  //  32 MiB

  p0_pre<<<16, 256, 0, stream>>>(state, A_w, A_b, C_w, C_b, sm, a_state, Mh, bias_f);
  p1_pre<<<80, 256, 0, stream>>>(Wo, Mh, bias_f, bo, Wb, constb);
  k4_ns<<<2048, 256, 0, stream>>>(x, sm, a_state, xb, out2);
  k5_gemm<<<256, 512, 0, stream>>>(xb, Wb, constb, out);
}